// Round 1
// baseline (164.018 us; speedup 1.0000x reference)
//
#include <hip/hip_runtime.h>
#include <hip/hip_bf16.h>

// GCN layer: out = relu( D^-1/2 (dedup(A) + I) D^-1/2 (X @ W) )
// N=10000, E=320000, F=256.
// Storage: fp32 X/W/out (PROVEN r9/r10: removing fp32 paths -> NaN->relu->0;
// restoring them passes at 1 bf16 ulp). Edges: int32 expected, int64 tolerated
// via per-wave ballot detect in k_fill (no flags buffer, no sync).
// Strategy: bf16-cast W once (Wt, transposed); GEMM reads fp32 X directly and
// converts A-fragments in-register (no Xb buffer, no cast pass).
// THIS ROUND: k_fill + k_dedup fused via test-and-set dedup bitmap (N*N bits
// = 12.5 MB in ws). Per edge one atomicOr; unique winner appends adj, bumps
// cnt[s] and deg[t]. Deletes one launch + the adj re-read/rewrite pass + the
// O(c*lane) LDS scan. 4 launches: k_pre(Wt + init + bitmap zero) -> k_fill
//             -> k_gemm_mfma(pure; r6: never merge other code into it)
//             -> k_gather (fp32 out).
// r8 lesson: no cooperative mega-kernel (occupancy cap cost 2x).
//
// ws layout (bytes), ~21.7 MB (ws is 256 MiB per harness poison fill):
//   deg   i32[N]       @ 0           (distinct in-degree + 1 self)
//   cnt   i32[N]       @ 40,960      (deduped out-degree)
//   adj   i32[N*96]    @ 81,920      (fixed-stride adjacency, deduped)
//   Wt    bf16[F*F]    @ 3,921,920   (W cast+transposed: Wt[n][k])
//   H     bf16[N*F]    @ 4,052,992   (bf16(X) @ bf16(W))
//   bm    u32[N*N/32]  @ 9,172,992   (dedup bitmap, 12.5 MB)

constexpr int N = 10000;
constexpr int E = 320000;
constexpr int F = 256;
constexpr int DEGCAP = 96;  // Poisson(32): P(any out-degree >= 96) ~ 1e-16

constexpr size_t OFF_DEG = 0;
constexpr size_t OFF_CNT = 40960;
constexpr size_t OFF_ADJ = 81920;
constexpr size_t OFF_WT  = OFF_ADJ + 4ull * N * DEGCAP;  // 3,921,920
constexpr size_t OFF_H   = OFF_WT + 2ull * F * F;        // 4,052,992
constexpr size_t OFF_BM  = OFF_H + 2ull * N * F;         // 9,172,992 (16-aligned)
constexpr int BM_WORDS = (N * N) / 32;                   // 3,125,000
constexpr int BM_U4    = BM_WORDS / 4;                   // 781,250 uint4 stores

typedef short s8v __attribute__((ext_vector_type(8)));   // 8 bf16 = 4 VGPRs
typedef float f4v __attribute__((ext_vector_type(4)));   // MFMA accumulator

__device__ __forceinline__ float bf2f(unsigned short u) {
    union { unsigned u; float f; } c; c.u = (unsigned)u << 16; return c.f;
}
__device__ __forceinline__ unsigned short f2bf(float f) {
    union { __hip_bfloat16 b; unsigned short s; } c; c.b = __float2bfloat16(f); return c.s;
}

// 256 blocks: cnt=0, deg=1 (+I self-loop); zero dedup bitmap (grid-stride);
// blocks 0-63: W (fp32) -> Wt (bf16, transposed).
__global__ void k_pre(int* __restrict__ deg, int* __restrict__ cnt,
                      const float* __restrict__ W, unsigned short* __restrict__ Wt,
                      uint4* __restrict__ bm) {
    __shared__ unsigned short ls[4][F];
    int i = blockIdx.x * blockDim.x + threadIdx.x;
    if (i < N) { deg[i] = 1; cnt[i] = 0; }

    // bitmap zero: 781,250 uint4 / 65,536 threads = 12 grid-stride iters (~2 us)
    uint4 z; z.x = 0u; z.y = 0u; z.z = 0u; z.w = 0u;
    for (int b = i; b < BM_U4; b += 256 * 256) bm[b] = z;

    if (blockIdx.x < 64) {
        int n0 = blockIdx.x * 4;  // this block owns W cols n0..n0+3 (Wt rows)
        int k = threadIdx.x;
        float4 v = *(const float4*)&W[k * F + n0];
        ls[0][k] = f2bf(v.x); ls[1][k] = f2bf(v.y);
        ls[2][k] = f2bf(v.z); ls[3][k] = f2bf(v.w);
        __syncthreads();
        int nn = threadIdx.x >> 6;
        int kk = (threadIdx.x & 63) * 4;
        uint2 o;
        o.x = (unsigned)ls[nn][kk]     | ((unsigned)ls[nn][kk + 1] << 16);
        o.y = (unsigned)ls[nn][kk + 2] | ((unsigned)ls[nn][kk + 3] << 16);
        *(uint2*)&Wt[(n0 + nn) * F + kk] = o;
    }
}

// Fused fill+dedup: one atomicOr on the (s,t) bit; first setter (unique per
// distinct edge) appends t to adj[s], bumps cnt[s] and deg[t]. Duplicate
// edges (~512 expected of 320k) lose the bit race and exit.
// Edge dtype detected per wave via ballot (no LDS, no sync): for int32
// storage, odd int32 words are edge ids (nonzero w.p. 1-1e-4 each); for
// int64, they are high halves == 0 (ids < 1e4).
__global__ void k_fill(const int* __restrict__ edges, int* __restrict__ cnt,
                       int* __restrict__ adj, int* __restrict__ deg,
                       unsigned* __restrict__ bm) {
    int probe = edges[2 * (threadIdx.x & 63) + 1];
    bool is32 = __ballot(probe != 0) != 0ull;  // wave-uniform
    int e = blockIdx.x * blockDim.x + threadIdx.x;
    if (e >= E) return;
    int s, t;
    if (is32) { s = edges[e];     t = edges[E + e]; }
    else      { s = edges[2 * e]; t = edges[2 * E + 2 * e]; }
    if ((unsigned)s >= (unsigned)N || (unsigned)t >= (unsigned)N) return;
    unsigned idx = (unsigned)s * (unsigned)N + (unsigned)t;  // < 1e8 < 2^31
    unsigned mask = 1u << (idx & 31);
    unsigned old = atomicOr(&bm[idx >> 5], mask);
    if (old & mask) return;  // duplicate edge: someone already owns this bit
    int p = atomicAdd(&cnt[s], 1);
    if (p < DEGCAP) adj[s * DEGCAP + p] = t;
    atomicAdd(&deg[t], 1);   // fire-and-forget (return value unused)
}

// H = bf16(X) @ bf16(W) via MFMA 16x16x32. One wave per 16-row strip
// (625 blocks). A-frag: X fp32 rows read directly (2x float4), converted to
// bf16 in-register. B-frag: Wt[t*16+(lane&15)][kk*32+q*8..+8] (L2-resident).
// C layout: col = lane&15, row = (lane>>4)*4 + reg  [learn_hip m89/m91].
// PURE kernel: r6 showed merging any other path in here costs 30x (regalloc).
__global__ void __launch_bounds__(64) k_gemm_mfma(
    const float* __restrict__ X, const unsigned short* __restrict__ Wt,
    unsigned short* __restrict__ H) {
    int lane = threadIdx.x;
    int r0 = blockIdx.x * 16;
    int m = lane & 15, q = lane >> 4;
    const float4* A = (const float4*)(X + (r0 + m) * F + q * 8);  // +kk*32 floats = +kk*8 float4
    const s8v* B = (const s8v*)(Wt + m * F + q * 8);
    f4v acc[16] = {};
#pragma unroll
    for (int kk = 0; kk < 8; ++kk) {
        float4 u = A[kk * 8];
        float4 v = A[kk * 8 + 1];
        s8v af;
        af[0] = (short)f2bf(u.x); af[1] = (short)f2bf(u.y);
        af[2] = (short)f2bf(u.z); af[3] = (short)f2bf(u.w);
        af[4] = (short)f2bf(v.x); af[5] = (short)f2bf(v.y);
        af[6] = (short)f2bf(v.z); af[7] = (short)f2bf(v.w);
#pragma unroll
        for (int t = 0; t < 16; ++t) {
            s8v bf = B[t * 512 + kk * 4];
            acc[t] = __builtin_amdgcn_mfma_f32_16x16x32_bf16(af, bf, acc[t], 0, 0, 0);
        }
    }
#pragma unroll
    for (int t = 0; t < 16; ++t) {
        int col = t * 16 + m;
#pragma unroll
        for (int i = 0; i < 4; ++i)
            H[(r0 + q * 4 + i) * F + col] = f2bf(acc[t][i]);
    }
}

#define ACC8(hv, dv)                                          \
    p0 += dv * bf2f((unsigned short)(hv.x & 0xFFFF));         \
    p1 += dv * bf2f((unsigned short)(hv.x >> 16));            \
    p2 += dv * bf2f((unsigned short)(hv.y & 0xFFFF));         \
    p3 += dv * bf2f((unsigned short)(hv.y >> 16));            \
    p4 += dv * bf2f((unsigned short)(hv.z & 0xFFFF));         \
    p5 += dv * bf2f((unsigned short)(hv.z >> 16));            \
    p6 += dv * bf2f((unsigned short)(hv.w & 0xFFFF));         \
    p7 += dv * bf2f((unsigned short)(hv.w >> 16));

// r7/r10-proven gather, fp32 output. One wave per node, half-wave neighbor
// pairing: lanes 0-31 even neighbors, 32-63 odd; 16B loads (8 feats), 4 rows
// in flight. Neighbor ids/dinv register-cached, shfl-broadcast (lanes >= c
// give d=0 padding). shfl-xor-32 reduction, fused norm + self-loop + ReLU.
__global__ void k_gather(const int* __restrict__ adj, const int* __restrict__ cnt,
                         const int* __restrict__ deg,
                         const unsigned short* __restrict__ H,
                         float* __restrict__ out) {
    int wave = threadIdx.x >> 6;
    int lane = threadIdx.x & 63;
    int s = blockIdx.x * 4 + wave;  // N = 2500*4 exactly
    int half = lane >> 5, hl = lane & 31;
    const uint4* H16 = (const uint4*)H;  // 8 bf16 per uint4; row stride 32
    float ds = rsqrtf((float)deg[s]);
    int c = cnt[s]; if (c > DEGCAP) c = DEGCAP;
    const int* a = adj + s * DEGCAP;
    int tl = 0; float dl = 0.0f;
    if (lane < c) { tl = a[lane]; dl = rsqrtf((float)deg[tl]); }

    uint4 hs = H16[s * 32 + hl];
    float p0, p1, p2, p3, p4, p5, p6, p7;
    {
        float w = half ? 0.0f : ds;  // self term once (half 0 only)
        p0 = w * bf2f((unsigned short)(hs.x & 0xFFFF));
        p1 = w * bf2f((unsigned short)(hs.x >> 16));
        p2 = w * bf2f((unsigned short)(hs.y & 0xFFFF));
        p3 = w * bf2f((unsigned short)(hs.y >> 16));
        p4 = w * bf2f((unsigned short)(hs.z & 0xFFFF));
        p5 = w * bf2f((unsigned short)(hs.z >> 16));
        p6 = w * bf2f((unsigned short)(hs.w & 0xFFFF));
        p7 = w * bf2f((unsigned short)(hs.w >> 16));
    }
    int cc = c < 64 ? c : 64;
    for (int i = 0; i < cc; i += 8) {  // 4 pairs = 8 neighbors per iter
        int i0 = i + half, i1 = i + 2 + half, i2 = i + 4 + half, i3 = i + 6 + half;
        int t0 = __shfl(tl, i0), t1 = __shfl(tl, i1);
        int t2 = __shfl(tl, i2), t3 = __shfl(tl, i3);
        float d0 = __shfl(dl, i0), d1 = __shfl(dl, i1);
        float d2 = __shfl(dl, i2), d3 = __shfl(dl, i3);
        uint4 h0 = H16[t0 * 32 + hl];
        uint4 h1 = H16[t1 * 32 + hl];
        uint4 h2 = H16[t2 * 32 + hl];
        uint4 h3 = H16[t3 * 32 + hl];
        ACC8(h0, d0) ACC8(h1, d1) ACC8(h2, d2) ACC8(h3, d3)
    }
    for (int i = 64; i < c; ++i) {  // rare: deduped degree > 64
        int t = a[i];
        float d = half ? 0.0f : rsqrtf((float)deg[t]);
        uint4 h = H16[t * 32 + hl];
        ACC8(h, d)
    }
    p0 += __shfl(p0, lane ^ 32); p1 += __shfl(p1, lane ^ 32);
    p2 += __shfl(p2, lane ^ 32); p3 += __shfl(p3, lane ^ 32);
    p4 += __shfl(p4, lane ^ 32); p5 += __shfl(p5, lane ^ 32);
    p6 += __shfl(p6, lane ^ 32); p7 += __shfl(p7, lane ^ 32);
    p0 = fmaxf(p0 * ds, 0.0f); p1 = fmaxf(p1 * ds, 0.0f);
    p2 = fmaxf(p2 * ds, 0.0f); p3 = fmaxf(p3 * ds, 0.0f);
    p4 = fmaxf(p4 * ds, 0.0f); p5 = fmaxf(p5 * ds, 0.0f);
    p6 = fmaxf(p6 * ds, 0.0f); p7 = fmaxf(p7 * ds, 0.0f);
    float4 o;
    if (half) { o.x = p4; o.y = p5; o.z = p6; o.w = p7; }
    else      { o.x = p0; o.y = p1; o.z = p2; o.w = p3; }
    ((float4*)out)[s * 64 + hl * 2 + half] = o;
}

extern "C" void kernel_launch(void* const* d_in, const int* in_sizes, int n_in,
                              void* d_out, int out_size, void* d_ws, size_t ws_size,
                              hipStream_t stream) {
    const float* X = (const float*)d_in[0];
    const float* W = (const float*)d_in[1];
    const int* edges = (const int*)d_in[2];

    char* ws = (char*)d_ws;
    int* deg           = (int*)(ws + OFF_DEG);
    int* cnt           = (int*)(ws + OFF_CNT);
    int* adj           = (int*)(ws + OFF_ADJ);
    unsigned short* Wt = (unsigned short*)(ws + OFF_WT);
    unsigned short* H  = (unsigned short*)(ws + OFF_H);
    unsigned* bm       = (unsigned*)(ws + OFF_BM);

    k_pre<<<256, 256, 0, stream>>>(deg, cnt, W, Wt, (uint4*)bm);
    k_fill<<<(E + 255) / 256, 256, 0, stream>>>(edges, cnt, adj, deg, bm);
    k_gemm_mfma<<<N / 16, 64, 0, stream>>>(X, Wt, H);
    k_gather<<<N / 4, 256, 0, stream>>>(adj, cnt, deg, H, (float*)d_out);
}

// Round 2
// 150.033 us; speedup vs baseline: 1.0932x; 1.0932x over previous
//
#include <hip/hip_runtime.h>
#include <hip/hip_bf16.h>

// GCN layer: out = relu( D^-1/2 (dedup(A) + I) D^-1/2 (X @ W) )
// N=10000, E=320000, F=256.
// Storage: fp32 X/W/out (PROVEN r9/r10: removing fp32 paths -> NaN->relu->0;
// restoring them passes at 1 bf16 ulp). Edges: int32 expected, int64 tolerated
// via per-wave ballot detect in k_fill (no flags buffer, no sync).
// Strategy: bf16-cast W once (Wt, transposed); GEMM reads fp32 X directly and
// converts A-fragments in-register (no Xb buffer, no cast pass).
// THIS ROUND (post-mortem r1: fused fill's dependent atomic chain
// atomicOr->atomicAdd->store was 51 us, latency-bound, VALUBusy 0.4%):
// ZERO returning atomics anywhere. k_fill does only fire-and-forget atomicOr
// into the dedup bitmap; new k_scan walks the bitmap (1 wave/node row,
// coalesced), popcount+wave-prefix-sum gives exact adj offsets and cnt with
// no cnt atomics at all; deg[t]++ is fire-and-forget. 5 launches:
//   k_pre(Wt + deg init + bitmap zero) -> k_fill(bitmap only)
//   -> k_scan(adj/cnt/deg) -> k_gemm_mfma(pure; r6) -> k_gather(fp32 out).
// r8 lesson: no cooperative mega-kernel (occupancy cap cost 2x).
//
// ws layout (bytes), ~22 MB (ws is 256 MiB per harness poison fill):
//   deg   i32[N]       @ 0           (distinct in-degree + 1 self)
//   cnt   i32[N]       @ 40,960      (deduped out-degree)
//   adj   i32[N*96]    @ 81,920      (fixed-stride adjacency, deduped)
//   Wt    bf16[F*F]    @ 3,921,920   (W cast+transposed: Wt[n][k])
//   H     bf16[N*F]    @ 4,052,992   (bf16(X) @ bf16(W))
//   bm    u32[N*320]   @ 9,172,992   (dedup bitmap, row stride 320 words
//                                     = 10240 bits >= N, word-aligned rows;
//                                     12.8 MB)

constexpr int N = 10000;
constexpr int E = 320000;
constexpr int F = 256;
constexpr int DEGCAP = 96;   // Poisson(32): P(any deduped degree >= 96) ~ 1e-16
constexpr int BMW = 320;     // bitmap words per row (10240 bits, rows aligned)

constexpr size_t OFF_DEG = 0;
constexpr size_t OFF_CNT = 40960;
constexpr size_t OFF_ADJ = 81920;
constexpr size_t OFF_WT  = OFF_ADJ + 4ull * N * DEGCAP;  // 3,921,920
constexpr size_t OFF_H   = OFF_WT + 2ull * F * F;        // 4,052,992
constexpr size_t OFF_BM  = OFF_H + 2ull * N * F;         // 9,172,992 (16-aligned)
constexpr int BM_WORDS = N * BMW;                        // 3,200,000
constexpr int BM_U4    = BM_WORDS / 4;                   // 800,000 uint4 stores

typedef short s8v __attribute__((ext_vector_type(8)));   // 8 bf16 = 4 VGPRs
typedef float f4v __attribute__((ext_vector_type(4)));   // MFMA accumulator

__device__ __forceinline__ float bf2f(unsigned short u) {
    union { unsigned u; float f; } c; c.u = (unsigned)u << 16; return c.f;
}
__device__ __forceinline__ unsigned short f2bf(float f) {
    union { __hip_bfloat16 b; unsigned short s; } c; c.b = __float2bfloat16(f); return c.s;
}

// 256 blocks: deg=1 (+I self-loop); zero dedup bitmap (grid-stride);
// blocks 0-63: W (fp32) -> Wt (bf16, transposed). cnt needs no init
// (k_scan writes every entry).
__global__ void k_pre(int* __restrict__ deg,
                      const float* __restrict__ W, unsigned short* __restrict__ Wt,
                      uint4* __restrict__ bm) {
    __shared__ unsigned short ls[4][F];
    int i = blockIdx.x * blockDim.x + threadIdx.x;
    if (i < N) deg[i] = 1;

    // bitmap zero: 800,000 uint4 / 65,536 threads = 13 grid-stride iters
    uint4 z; z.x = 0u; z.y = 0u; z.z = 0u; z.w = 0u;
    for (int b = i; b < BM_U4; b += 256 * 256) bm[b] = z;

    if (blockIdx.x < 64) {
        int n0 = blockIdx.x * 4;  // this block owns W cols n0..n0+3 (Wt rows)
        int k = threadIdx.x;
        float4 v = *(const float4*)&W[k * F + n0];
        ls[0][k] = f2bf(v.x); ls[1][k] = f2bf(v.y);
        ls[2][k] = f2bf(v.z); ls[3][k] = f2bf(v.w);
        __syncthreads();
        int nn = threadIdx.x >> 6;
        int kk = (threadIdx.x & 63) * 4;
        uint2 o;
        o.x = (unsigned)ls[nn][kk]     | ((unsigned)ls[nn][kk + 1] << 16);
        o.y = (unsigned)ls[nn][kk + 2] | ((unsigned)ls[nn][kk + 3] << 16);
        *(uint2*)&Wt[(n0 + nn) * F + kk] = o;
    }
}

// Bitmap fill: ONE fire-and-forget atomicOr per edge (result unused ->
// non-returning global_atomic_or, no latency chain, pure throughput).
// Edge dtype detected per wave via ballot (no LDS, no sync): for int32
// storage, odd int32 words are edge ids (nonzero w.p. 1-1e-4 each); for
// int64, they are high halves == 0 (ids < 1e4).
__global__ void k_fill(const int* __restrict__ edges, unsigned* __restrict__ bm) {
    int probe = edges[2 * (threadIdx.x & 63) + 1];
    bool is32 = __ballot(probe != 0) != 0ull;  // wave-uniform
    int e = blockIdx.x * blockDim.x + threadIdx.x;
    if (e >= E) return;
    int s, t;
    if (is32) { s = edges[e];     t = edges[E + e]; }
    else      { s = edges[2 * e]; t = edges[2 * E + 2 * e]; }
    if ((unsigned)s >= (unsigned)N || (unsigned)t >= (unsigned)N) return;
    unsigned idx = (unsigned)s * (unsigned)(BMW * 32) + (unsigned)t;  // < 1.03e8
    atomicOr(&bm[idx >> 5], 1u << (idx & 31));  // fire-and-forget
}

// Bitmap scan: one wave per node row (2500 blocks x 4 waves). Coalesced
// 5x stride-64 word loads (1280 B/row), popcount + wave inclusive prefix
// sum (shfl) -> exact exclusive adj offsets and cnt (NO cnt atomics).
// Set bits -> adj targets; deg[t]++ fire-and-forget. Words 313..319 of each
// row are never set (t < 10000) so the 320-word pad is harmless.
__global__ void k_scan(const unsigned* __restrict__ bm, int* __restrict__ adj,
                       int* __restrict__ cnt, int* __restrict__ deg) {
    int wave = threadIdx.x >> 6, lane = threadIdx.x & 63;
    int s = blockIdx.x * 4 + wave;  // N = 2500*4 exactly
    const unsigned* row = bm + (size_t)s * BMW;
    unsigned w0 = row[lane];
    unsigned w1 = row[lane + 64];
    unsigned w2 = row[lane + 128];
    unsigned w3 = row[lane + 192];
    unsigned w4 = row[lane + 256];
    int pc = __popc(w0) + __popc(w1) + __popc(w2) + __popc(w3) + __popc(w4);
    int sc = pc;
#pragma unroll
    for (int d = 1; d < 64; d <<= 1) {
        int v = __shfl_up(sc, d);
        if (lane >= d) sc += v;
    }
    int o = sc - pc;  // exclusive prefix = this lane's first adj slot
    if (lane == 63) cnt[s] = sc < DEGCAP ? sc : DEGCAP;
    int* arow = adj + s * DEGCAP;
    unsigned wv[5] = {w0, w1, w2, w3, w4};
#pragma unroll
    for (int j = 0; j < 5; ++j) {
        unsigned w = wv[j];
        int base = (j * 64 + lane) * 32;
        while (w) {
            int b = __ffs(w) - 1;
            w &= w - 1;
            int t = base + b;
            if (o < DEGCAP) arow[o] = t;
            ++o;
            atomicAdd(&deg[t], 1);  // fire-and-forget
        }
    }
}

// H = bf16(X) @ bf16(W) via MFMA 16x16x32. One wave per 16-row strip
// (625 blocks). A-frag: X fp32 rows read directly (2x float4), converted to
// bf16 in-register. B-frag: Wt[t*16+(lane&15)][kk*32+q*8..+8] (L2-resident).
// C layout: col = lane&15, row = (lane>>4)*4 + reg  [learn_hip m89/m91].
// PURE kernel: r6 showed merging any other path in here costs 30x (regalloc).
__global__ void __launch_bounds__(64) k_gemm_mfma(
    const float* __restrict__ X, const unsigned short* __restrict__ Wt,
    unsigned short* __restrict__ H) {
    int lane = threadIdx.x;
    int r0 = blockIdx.x * 16;
    int m = lane & 15, q = lane >> 4;
    const float4* A = (const float4*)(X + (r0 + m) * F + q * 8);  // +kk*32 floats = +kk*8 float4
    const s8v* B = (const s8v*)(Wt + m * F + q * 8);
    f4v acc[16] = {};
#pragma unroll
    for (int kk = 0; kk < 8; ++kk) {
        float4 u = A[kk * 8];
        float4 v = A[kk * 8 + 1];
        s8v af;
        af[0] = (short)f2bf(u.x); af[1] = (short)f2bf(u.y);
        af[2] = (short)f2bf(u.z); af[3] = (short)f2bf(u.w);
        af[4] = (short)f2bf(v.x); af[5] = (short)f2bf(v.y);
        af[6] = (short)f2bf(v.z); af[7] = (short)f2bf(v.w);
#pragma unroll
        for (int t = 0; t < 16; ++t) {
            s8v bf = B[t * 512 + kk * 4];
            acc[t] = __builtin_amdgcn_mfma_f32_16x16x32_bf16(af, bf, acc[t], 0, 0, 0);
        }
    }
#pragma unroll
    for (int t = 0; t < 16; ++t) {
        int col = t * 16 + m;
#pragma unroll
        for (int i = 0; i < 4; ++i)
            H[(r0 + q * 4 + i) * F + col] = f2bf(acc[t][i]);
    }
}

#define ACC8(hv, dv)                                          \
    p0 += dv * bf2f((unsigned short)(hv.x & 0xFFFF));         \
    p1 += dv * bf2f((unsigned short)(hv.x >> 16));            \
    p2 += dv * bf2f((unsigned short)(hv.y & 0xFFFF));         \
    p3 += dv * bf2f((unsigned short)(hv.y >> 16));            \
    p4 += dv * bf2f((unsigned short)(hv.z & 0xFFFF));         \
    p5 += dv * bf2f((unsigned short)(hv.z >> 16));            \
    p6 += dv * bf2f((unsigned short)(hv.w & 0xFFFF));         \
    p7 += dv * bf2f((unsigned short)(hv.w >> 16));

// r7/r10-proven gather, fp32 output. One wave per node, half-wave neighbor
// pairing: lanes 0-31 even neighbors, 32-63 odd; 16B loads (8 feats), 4 rows
// in flight. Neighbor ids/dinv register-cached, shfl-broadcast (lanes >= c
// give d=0 padding). shfl-xor-32 reduction, fused norm + self-loop + ReLU.
__global__ void k_gather(const int* __restrict__ adj, const int* __restrict__ cnt,
                         const int* __restrict__ deg,
                         const unsigned short* __restrict__ H,
                         float* __restrict__ out) {
    int wave = threadIdx.x >> 6;
    int lane = threadIdx.x & 63;
    int s = blockIdx.x * 4 + wave;  // N = 2500*4 exactly
    int half = lane >> 5, hl = lane & 31;
    const uint4* H16 = (const uint4*)H;  // 8 bf16 per uint4; row stride 32
    float ds = rsqrtf((float)deg[s]);
    int c = cnt[s]; if (c > DEGCAP) c = DEGCAP;
    const int* a = adj + s * DEGCAP;
    int tl = 0; float dl = 0.0f;
    if (lane < c) { tl = a[lane]; dl = rsqrtf((float)deg[tl]); }

    uint4 hs = H16[s * 32 + hl];
    float p0, p1, p2, p3, p4, p5, p6, p7;
    {
        float w = half ? 0.0f : ds;  // self term once (half 0 only)
        p0 = w * bf2f((unsigned short)(hs.x & 0xFFFF));
        p1 = w * bf2f((unsigned short)(hs.x >> 16));
        p2 = w * bf2f((unsigned short)(hs.y & 0xFFFF));
        p3 = w * bf2f((unsigned short)(hs.y >> 16));
        p4 = w * bf2f((unsigned short)(hs.z & 0xFFFF));
        p5 = w * bf2f((unsigned short)(hs.z >> 16));
        p6 = w * bf2f((unsigned short)(hs.w & 0xFFFF));
        p7 = w * bf2f((unsigned short)(hs.w >> 16));
    }
    int cc = c < 64 ? c : 64;
    for (int i = 0; i < cc; i += 8) {  // 4 pairs = 8 neighbors per iter
        int i0 = i + half, i1 = i + 2 + half, i2 = i + 4 + half, i3 = i + 6 + half;
        int t0 = __shfl(tl, i0), t1 = __shfl(tl, i1);
        int t2 = __shfl(tl, i2), t3 = __shfl(tl, i3);
        float d0 = __shfl(dl, i0), d1 = __shfl(dl, i1);
        float d2 = __shfl(dl, i2), d3 = __shfl(dl, i3);
        uint4 h0 = H16[t0 * 32 + hl];
        uint4 h1 = H16[t1 * 32 + hl];
        uint4 h2 = H16[t2 * 32 + hl];
        uint4 h3 = H16[t3 * 32 + hl];
        ACC8(h0, d0) ACC8(h1, d1) ACC8(h2, d2) ACC8(h3, d3)
    }
    for (int i = 64; i < c; ++i) {  // rare: deduped degree > 64
        int t = a[i];
        float d = half ? 0.0f : rsqrtf((float)deg[t]);
        uint4 h = H16[t * 32 + hl];
        ACC8(h, d)
    }
    p0 += __shfl(p0, lane ^ 32); p1 += __shfl(p1, lane ^ 32);
    p2 += __shfl(p2, lane ^ 32); p3 += __shfl(p3, lane ^ 32);
    p4 += __shfl(p4, lane ^ 32); p5 += __shfl(p5, lane ^ 32);
    p6 += __shfl(p6, lane ^ 32); p7 += __shfl(p7, lane ^ 32);
    p0 = fmaxf(p0 * ds, 0.0f); p1 = fmaxf(p1 * ds, 0.0f);
    p2 = fmaxf(p2 * ds, 0.0f); p3 = fmaxf(p3 * ds, 0.0f);
    p4 = fmaxf(p4 * ds, 0.0f); p5 = fmaxf(p5 * ds, 0.0f);
    p6 = fmaxf(p6 * ds, 0.0f); p7 = fmaxf(p7 * ds, 0.0f);
    float4 o;
    if (half) { o.x = p4; o.y = p5; o.z = p6; o.w = p7; }
    else      { o.x = p0; o.y = p1; o.z = p2; o.w = p3; }
    ((float4*)out)[s * 64 + hl * 2 + half] = o;
}

extern "C" void kernel_launch(void* const* d_in, const int* in_sizes, int n_in,
                              void* d_out, int out_size, void* d_ws, size_t ws_size,
                              hipStream_t stream) {
    const float* X = (const float*)d_in[0];
    const float* W = (const float*)d_in[1];
    const int* edges = (const int*)d_in[2];

    char* ws = (char*)d_ws;
    int* deg           = (int*)(ws + OFF_DEG);
    int* cnt           = (int*)(ws + OFF_CNT);
    int* adj           = (int*)(ws + OFF_ADJ);
    unsigned short* Wt = (unsigned short*)(ws + OFF_WT);
    unsigned short* H  = (unsigned short*)(ws + OFF_H);
    unsigned* bm       = (unsigned*)(ws + OFF_BM);

    k_pre<<<256, 256, 0, stream>>>(deg, W, Wt, (uint4*)bm);
    k_fill<<<(E + 255) / 256, 256, 0, stream>>>(edges, bm);
    k_scan<<<N / 4, 256, 0, stream>>>(bm, adj, cnt, deg);
    k_gemm_mfma<<<N / 16, 64, 0, stream>>>(X, Wt, H);
    k_gather<<<N / 4, 256, 0, stream>>>(adj, cnt, deg, H, (float*)d_out);
}